// Round 9
// baseline (183.388 us; speedup 1.0000x reference)
//
#include <hip/hip_runtime.h>

// ---------------------------------------------------------------------------
// SE3 conv layer, 4-kernel pipeline (+1 memset):
//   prep:  bfrag pre-pack (f16 B-fragments of W2/32) + dst histogram
//   scan:  exclusive offsets (single block, chunk-serial)
//   edge:  h = silu(radial@W1/4) -> f16-MFMA contraction -> claims CSR slot
//          (atomic cursor) -> writes mix row (f16, 128 B) + sh row (f16, 20 B)
//   gather: per-node wave, fully linear segmented reduction + self-interaction
// ws: [ mix E*64 f16 | offs N+1 | curs N | shs E*10 f16 | (align) bfrag 96KB ]
// ---------------------------------------------------------------------------

typedef _Float16 f16x2 __attribute__((ext_vector_type(2)));
typedef _Float16 f16x8 __attribute__((ext_vector_type(8)));
typedef __fp16  g16x2 __attribute__((ext_vector_type(2)));   // cvt_pkrtz result type
typedef float f32x4 __attribute__((ext_vector_type(4)));

union AFrag { unsigned int u[4]; f16x2 h2[4]; f16x8 v; };
union BFrag { uint4 u4; f16x8 v; };
union HW { g16x2 g; f16x2 f; unsigned int u; };

// ---------------------- prep: bfrag pack + histogram ------------------------
// Bfrag[f][lane][j], f = ks*3+nt, ku = ks*32 + (lane>>4)*8 + j,
// k=ku>>4, u=ku&15, n = nt*16 + (lane&15), l=n>>4, v=n&15; val = W2/32.

__global__ __launch_bounds__(256)
void prep_kernel(const float* __restrict__ W2, _Float16* __restrict__ bfrag,
                 const int* __restrict__ ei, int* __restrict__ counts, int E) {
    int t = blockIdx.x * 256 + threadIdx.x;
    if (t < E) atomicAdd(&counts[ei[E + t] + 1], 1);
    if (t < 96 * 512) {
        int f = t >> 9;
        int rr = t & 511;
        int lane = rr >> 3, j = rr & 7;
        int ks = f / 3, nt = f - 3 * ks;
        int q = lane >> 4, c = lane & 15;
        int ku = ks * 32 + q * 8 + j;
        int k = ku >> 4, u = ku & 15;
        int n = nt * 16 + c;
        int l = n >> 4, v = n & 15;
        float val = W2[(size_t)k * 768 + l * 256 + u * 16 + v] * 0.03125f;
        bfrag[t] = (_Float16)val;
    }
}

// chunk-serial scan: 1 block, each thread owns ceil(n/1024) contiguous elems.
__global__ __launch_bounds__(1024)
void scan_kernel(int* __restrict__ data, int n) {
    __shared__ int wsum[16];
    int tid = threadIdx.x, lane = tid & 63, wid = tid >> 6;
    int ch = (n + 1023) >> 10;
    int beg = tid * ch;
    int end = beg + ch; if (end > n) end = n;

    int s = 0;
    for (int i = beg; i < end; ++i) s += data[i];

    int v = s;
    #pragma unroll
    for (int off = 1; off < 64; off <<= 1) {
        int t = __shfl_up(v, off, 64);
        if (lane >= off) v += t;
    }
    if (lane == 63) wsum[wid] = v;
    __syncthreads();
    if (wid == 0 && lane < 16) {
        int w = wsum[lane];
        #pragma unroll
        for (int off = 1; off < 16; off <<= 1) {
            int t = __shfl_up(w, off, 16);
            if (lane >= off) w += t;
        }
        wsum[lane] = w;
    }
    __syncthreads();
    int run = (v - s) + (wid > 0 ? wsum[wid - 1] : 0);   // exclusive offset
    for (int i = beg; i < end; ++i) {
        run += data[i];
        data[i] = run;
    }
}

// --------------------------- MFMA edge kernel ------------------------------
// block = 256 = 4 waves; wave owns 64 edges (4 M-tiles of 16).

__global__ __launch_bounds__(256, 4)
void edge_mfma_kernel(const float* __restrict__ nf, const int* __restrict__ ei,
                      const float* __restrict__ radial, const float* __restrict__ W1,
                      const float* __restrict__ sh,
                      const _Float16* __restrict__ bfrag,
                      const int* __restrict__ offs, int* __restrict__ curs,
                      _Float16* __restrict__ mixs, _Float16* __restrict__ shs, int E) {
    __shared__ unsigned int h_lds[4][64][32];   // f16 pairs (k=2t,2t+1), XOR-swizzled
    __shared__ float w1t[64][16];               // W1^T, pre-scaled by 1/4

    int tid = threadIdx.x;

    // stage W1^T (scaled) into LDS once per block
    for (int idx = tid; idx < 1024; idx += 256) {
        int k = idx >> 4, u = idx & 15;
        w1t[k][u] = W1[u * 64 + k] * 0.25f;
    }
    __syncthreads();

    int wave = tid >> 6;
    int lane = tid & 63;
    int r_ = lane & 15;
    int q  = lane >> 4;
    int qh = q >> 1;                 // which half of the h-pair this lane needs
    int ul = (q & 1) * 8;            // u base for A-frag
    unsigned int sel = qh ? 0x03020302u : 0x01000100u;   // v_perm dup selector

    int ebase = blockIdx.x * 256 + wave * 64;

    // ---- phase 0: x rows for the wave's 4 M-tiles (issue early), f16 pack ----
    HW xp[4][4];
    #pragma unroll
    for (int m = 0; m < 4; ++m) {
        int e = ebase + m * 16 + r_; if (e >= E) e = E - 1;
        int src = ei[e];
        const float* xpp = nf + (size_t)src * 16 + ul;
        float4 a = *(const float4*)xpp;
        float4 b = *(const float4*)(xpp + 4);
        xp[m][0].g = __builtin_amdgcn_cvt_pkrtz(a.x, a.y);
        xp[m][1].g = __builtin_amdgcn_cvt_pkrtz(a.z, a.w);
        xp[m][2].g = __builtin_amdgcn_cvt_pkrtz(b.x, b.y);
        xp[m][3].g = __builtin_amdgcn_cvt_pkrtz(b.z, b.w);
    }

    // ---- phase 1: lane = edge; k-loop with W1^T broadcast reads ----
    {
        int e = ebase + lane; if (e >= E) e = E - 1;
        const float* rp = radial + (size_t)e * 16;
        float4 r0 = *(const float4*)(rp);
        float4 r1 = *(const float4*)(rp + 4);
        float4 r2 = *(const float4*)(rp + 8);
        float4 r3 = *(const float4*)(rp + 12);
        int swz = lane & 31;
        float hprev = 0.0f;
        #pragma unroll 8
        for (int k = 0; k < 64; ++k) {
            const float4* wr = (const float4*)(&w1t[k][0]);
            float4 w0 = wr[0], w1v = wr[1], w2v = wr[2], w3v = wr[3];
            float z = r0.x * w0.x;
            z = fmaf(r0.y, w0.y, z);  z = fmaf(r0.z, w0.z, z);  z = fmaf(r0.w, w0.w, z);
            z = fmaf(r1.x, w1v.x, z); z = fmaf(r1.y, w1v.y, z); z = fmaf(r1.z, w1v.z, z); z = fmaf(r1.w, w1v.w, z);
            z = fmaf(r2.x, w2v.x, z); z = fmaf(r2.y, w2v.y, z); z = fmaf(r2.z, w2v.z, z); z = fmaf(r2.w, w2v.w, z);
            z = fmaf(r3.x, w3v.x, z); z = fmaf(r3.y, w3v.y, z); z = fmaf(r3.z, w3v.z, z); z = fmaf(r3.w, w3v.w, z);
            float h = z * __builtin_amdgcn_rcpf(1.0f + __expf(-z));   // silu
            if (k & 1) {
                HW w; w.g = __builtin_amdgcn_cvt_pkrtz(hprev, h);     // (k-1, k)
                h_lds[wave][lane][(k >> 1) ^ swz] = w.u;
            } else {
                hprev = h;
            }
        }
    }
    // h_lds is per-wave private; within-wave program order suffices (no barrier)

    // ---- phase 3: K-loop, 32 steps of K=32 ----
    f32x4 acc[4][3];
    #pragma unroll
    for (int m = 0; m < 4; ++m)
        #pragma unroll
        for (int nt = 0; nt < 3; ++nt)
            acc[m][nt] = (f32x4){0.f, 0.f, 0.f, 0.f};

    #pragma unroll 2
    for (int ks = 0; ks < 32; ++ks) {
        BFrag b[3];
        #pragma unroll
        for (int nt = 0; nt < 3; ++nt)
            b[nt].u4 = *(const uint4*)(bfrag + (size_t)(ks * 3 + nt) * 512 + lane * 8);
        #pragma unroll
        for (int m = 0; m < 4; ++m) {
            int el = m * 16 + r_;
            unsigned int hw = h_lds[wave][el][ks ^ (el & 31)];
            HW hv; hv.u = __builtin_amdgcn_perm(hw, hw, sel);  // dup needed half
            AFrag a;
            #pragma unroll
            for (int p2 = 0; p2 < 4; ++p2)
                a.h2[p2] = hv.f * xp[m][p2].f;                 // v_pk_mul_f16
            #pragma unroll
            for (int nt = 0; nt < 3; ++nt)
                acc[m][nt] = __builtin_amdgcn_mfma_f32_16x16x32_f16(a.v, b[nt].v, acc[m][nt], 0, 0, 0);
        }
    }

    // ---- epilogue: claim CSR slot, write f16 mix row + f16 sh row ----
    // C layout: col=lane&15 (=r_), row=(lane>>4)*4+i (edge within m-tile).
    // row p (128 B): u32[r_] = (l0[r_], l1[r_]); f16[32+r_] = l2[r_].
    unsigned int* mixu = (unsigned int*)mixs;
    #pragma unroll
    for (int m = 0; m < 4; ++m) {
        #pragma unroll
        for (int i = 0; i < 4; ++i) {
            int e = ebase + m * 16 + q * 4 + i;
            bool valid = (e < E);
            int p = 0;
            if (r_ == 0 && valid) {
                int dst = ei[E + e];
                p = offs[dst] + atomicAdd(&curs[dst], 1);
            }
            p = __shfl(p, q * 16, 64);        // broadcast within q-group
            if (valid) {
                HW pr; pr.g = __builtin_amdgcn_cvt_pkrtz(acc[m][0][i], acc[m][1][i]);
                mixu[(size_t)p * 32 + r_] = pr.u;
                mixs[(size_t)p * 64 + 32 + r_] = (_Float16)acc[m][2][i];
                if (r_ < 9)
                    shs[(size_t)p * 10 + r_] = (_Float16)sh[(size_t)e * 9 + r_];
            }
        }
    }
}

// ------------------------------ gather -------------------------------------
// mix (f16, 128-B rows) and sh (f16, 20-B rows) in CSR order -> linear reads.

__global__ __launch_bounds__(256)
void gather_kernel(const _Float16* __restrict__ mixs, const _Float16* __restrict__ shs,
                   const int* __restrict__ offs,
                   const float* __restrict__ nf, const float* __restrict__ Wsi,
                   float* __restrict__ out, int N) {
    int node = blockIdx.x * 4 + (threadIdx.x >> 6);
    if (node >= N) return;
    int lane = threadIdx.x & 63;

    // channel c -> (f16 half-index within 64-half mix row, sh index)
    auto chmap = [](int c, int& hi, int& si) {
        if (c < 16)      { hi = 2 * c;           si = 0; }
        else if (c < 64) { int t = c - 16; hi = 2 * (t / 3) + 1; si = 1 + t % 3; }
        else             { int t = c - 64; hi = 32 + t / 5;      si = 4 + t % 5; }
    };
    int hi0, si0, hi1, si1, hi2 = 0, si2 = 0;
    chmap(lane, hi0, si0);
    chmap(lane + 64, hi1, si1);
    if (lane < 16) chmap(lane + 128, hi2, si2);

    float a0 = 0.f, a1 = 0.f, a2 = 0.f;
    float b0 = 0.f, b1 = 0.f, b2 = 0.f;
    float c0 = 0.f, c1 = 0.f, c2 = 0.f;
    float d0 = 0.f, d1 = 0.f, d2 = 0.f;
    int off = offs[node], end = offs[node + 1];
    int i = off;
    for (; i + 3 < end; i += 4) {
        const _Float16* m0 = mixs + (size_t)i * 64;
        const _Float16* m1 = m0 + 64;
        const _Float16* m2 = m0 + 128;
        const _Float16* m3 = m0 + 192;
        const _Float16* s0 = shs + (size_t)i * 10;
        const _Float16* s1 = s0 + 10;
        const _Float16* s2 = s0 + 20;
        const _Float16* s3 = s0 + 30;
        a0 = fmaf((float)m0[hi0], (float)s0[si0], a0);
        b0 = fmaf((float)m1[hi0], (float)s1[si0], b0);
        c0 = fmaf((float)m2[hi0], (float)s2[si0], c0);
        d0 = fmaf((float)m3[hi0], (float)s3[si0], d0);
        a1 = fmaf((float)m0[hi1], (float)s0[si1], a1);
        b1 = fmaf((float)m1[hi1], (float)s1[si1], b1);
        c1 = fmaf((float)m2[hi1], (float)s2[si1], c1);
        d1 = fmaf((float)m3[hi1], (float)s3[si1], d1);
        if (lane < 16) {
            a2 = fmaf((float)m0[hi2], (float)s0[si2], a2);
            b2 = fmaf((float)m1[hi2], (float)s1[si2], b2);
            c2 = fmaf((float)m2[hi2], (float)s2[si2], c2);
            d2 = fmaf((float)m3[hi2], (float)s3[si2], d2);
        }
    }
    for (; i < end; ++i) {
        const _Float16* m0 = mixs + (size_t)i * 64;
        const _Float16* s0 = shs + (size_t)i * 10;
        a0 = fmaf((float)m0[hi0], (float)s0[si0], a0);
        a1 = fmaf((float)m0[hi1], (float)s0[si1], a1);
        if (lane < 16) a2 = fmaf((float)m0[hi2], (float)s0[si2], a2);
    }
    a0 += b0 + c0 + d0;
    a1 += b1 + c1 + d1;
    a2 += b2 + c2 + d2;

    if (lane < 16) {   // self-interaction, 0e->0e only
        const float* xr = nf + (size_t)node * 16;
        float si = 0.0f;
        #pragma unroll
        for (int u = 0; u < 16; ++u)
            si = fmaf(xr[u], Wsi[u * 16 + lane], si);
        a0 = fmaf(si, 0.25f, a0);
    }

    float* orow = out + (size_t)node * 144;
    orow[lane] = a0;
    orow[lane + 64] = a1;
    if (lane < 16) orow[lane + 128] = a2;
}

// ------------------------- fallback (atomic path) --------------------------

__global__ __launch_bounds__(256)
void si_init_kernel(const float* __restrict__ nf, const float* __restrict__ Wsi,
                    float* __restrict__ out, int N) {
    int t = blockIdx.x * blockDim.x + threadIdx.x;
    int total = N * 144;
    if (t >= total) return;
    int n = t / 144;
    int c = t - n * 144;
    float val = 0.0f;
    if (c < 16) {
        const float* xr = nf + n * 16;
        #pragma unroll
        for (int u = 0; u < 16; ++u)
            val = fmaf(xr[u], Wsi[u * 16 + c], val);
        val *= 0.25f;
    }
    out[t] = val;
}

__global__ __launch_bounds__(256)
void edge_kernel_atomic(const float* __restrict__ nf, const int* __restrict__ ei,
                        const float* __restrict__ sh, const float* __restrict__ radial,
                        const float* __restrict__ W1, const float* __restrict__ W2,
                        float* __restrict__ out, int E) {
    int e = blockIdx.x * blockDim.x + threadIdx.x;
    if (e >= E) return;
    int src = ei[e];
    int dst = ei[E + e];
    float r[16], x[16];
    #pragma unroll
    for (int u = 0; u < 16; ++u) r[u] = radial[e * 16 + u] * 0.25f;
    #pragma unroll
    for (int u = 0; u < 16; ++u) x[u] = nf[src * 16 + u] * 0.03125f;
    float acc[48];
    #pragma unroll
    for (int j = 0; j < 48; ++j) acc[j] = 0.0f;
    for (int k = 0; k < 64; ++k) {
        float z = 0.0f;
        #pragma unroll
        for (int u = 0; u < 16; ++u) z = fmaf(r[u], W1[u * 64 + k], z);
        float hk = z / (1.0f + __expf(-z));
        const float* w2k = W2 + k * 768;
        #pragma unroll 4
        for (int u = 0; u < 16; ++u) {
            float p = hk * x[u];
            const float* w = w2k + u * 16;
            #pragma unroll
            for (int l = 0; l < 3; ++l)
                #pragma unroll
                for (int v = 0; v < 16; ++v)
                    acc[l * 16 + v] = fmaf(p, w[l * 256 + v], acc[l * 16 + v]);
        }
    }
    const float* she = sh + e * 9;
    float* orow = out + (long)dst * 144;
    #pragma unroll
    for (int v = 0; v < 16; ++v) atomicAdd(&orow[v], acc[v] * she[0]);
    #pragma unroll
    for (int v = 0; v < 16; ++v)
        for (int m = 0; m < 3; ++m)
            atomicAdd(&orow[16 + v * 3 + m], acc[16 + v] * she[1 + m]);
    #pragma unroll
    for (int v = 0; v < 16; ++v)
        for (int m = 0; m < 5; ++m)
            atomicAdd(&orow[64 + v * 5 + m], acc[32 + v] * she[4 + m]);
}

// ---------------------------------------------------------------------------

extern "C" void kernel_launch(void* const* d_in, const int* in_sizes, int n_in,
                              void* d_out, int out_size, void* d_ws, size_t ws_size,
                              hipStream_t stream) {
    const float* nf     = (const float*)d_in[0];
    const int*   ei     = (const int*)  d_in[1];
    const float* sh     = (const float*)d_in[2];
    const float* radial = (const float*)d_in[3];
    const float* W1     = (const float*)d_in[4];
    const float* W2     = (const float*)d_in[5];
    const float* Wsi    = (const float*)d_in[6];
    float* out = (float*)d_out;

    const int N = in_sizes[0] / 16;
    const int E = in_sizes[1] / 2;

    size_t mix_bytes  = (size_t)E * 64 * sizeof(_Float16);   // 128-B padded f16 rows
    size_t offs_bytes = (size_t)(N + 1) * sizeof(int);
    size_t curs_bytes = (size_t)N * sizeof(int);
    size_t shs_bytes  = (size_t)E * 10 * sizeof(_Float16);   // 20-B f16 sh rows
    size_t bfrag_off  = (mix_bytes + offs_bytes + curs_bytes + shs_bytes + 127) & ~(size_t)127;
    size_t bfrag_bytes = 96 * 512 * sizeof(_Float16);        // 96 KB
    size_t need = bfrag_off + bfrag_bytes;

    if (ws_size < need) {
        int total = N * 144;
        hipLaunchKernelGGL(si_init_kernel, dim3((total + 255) / 256), dim3(256), 0, stream,
                           nf, Wsi, out, N);
        hipLaunchKernelGGL(edge_kernel_atomic, dim3((E + 255) / 256), dim3(256), 0, stream,
                           nf, ei, sh, radial, W1, W2, out, E);
        return;
    }

    char* wsb = (char*)d_ws;
    _Float16* mixs = (_Float16*)wsb;
    int*   offs = (int*)(wsb + mix_bytes);
    int*   curs = (int*)(wsb + mix_bytes + offs_bytes);
    _Float16* shs = (_Float16*)(wsb + mix_bytes + offs_bytes + curs_bytes);
    _Float16* bfrag = (_Float16*)(wsb + bfrag_off);

    (void)hipMemsetAsync(offs, 0, offs_bytes + curs_bytes, stream);

    int eb = (E + 255) / 256;
    hipLaunchKernelGGL(prep_kernel, dim3(eb), dim3(256), 0, stream, W2, bfrag, ei, offs, E);
    hipLaunchKernelGGL(scan_kernel, dim3(1), dim3(1024), 0, stream, offs, N + 1);
    hipLaunchKernelGGL(edge_mfma_kernel, dim3(eb), dim3(256), 0, stream,
                       nf, ei, radial, W1, sh, bfrag, offs, curs, mixs, shs, E);
    hipLaunchKernelGGL(gather_kernel, dim3((N + 3) / 4), dim3(256), 0, stream,
                       mixs, shs, offs, nf, Wsi, out, N);
}